// Round 1
// baseline (369.010 us; speedup 1.0000x reference)
//
#include <hip/hip_runtime.h>

typedef __bf16 bf16_t;
typedef __bf16 bf16x8 __attribute__((ext_vector_type(8)));
typedef __bf16 bf16x4 __attribute__((ext_vector_type(4)));
typedef float  f32x4  __attribute__((ext_vector_type(4)));

#define B_      16
#define L_      2048
#define D_      128
#define QT      32
#define PITCH   2056            // bf16 elems per LDS score row (16B-aligned rows, +8 pad for bank spread)
#define NEGINF  (-1.0e9f)
#define SCALE   0.08838834764831845f   // 1/sqrt(128)

__global__ __launch_bounds__(512) void sdpa_kernel(
    const float* __restrict__ q, const float* __restrict__ k,
    const float* __restrict__ v, const int* __restrict__ mask,
    float* __restrict__ out, float* __restrict__ attn)
{
    __shared__ bf16_t sc[QT * PITCH];   // 131,584 B: 32 rows x 2048 scores (bf16) + pad
    __shared__ float  inv_l[QT];

    const int tid = threadIdx.x;
    const int w   = tid >> 6;           // wave 0..7
    const int l   = tid & 63;
    const int li  = l & 15;             // lane-in-16
    const int lg  = l >> 4;             // group 0..3

    const int b     = blockIdx.x >> 6;  // 64 q-tiles per batch
    const int qtile = blockIdx.x & 63;
    const int qbase = qtile * QT;

    const size_t bq = (size_t)b * L_;
    const float* qp    = q    + (bq + qbase) * (size_t)D_;
    const float* kp    = k    + bq * (size_t)D_;
    const float* vp    = v    + bq * (size_t)D_;
    const int*   mp    = mask + (bq + qbase) * (size_t)L_;
    float*       outp  = out  + (bq + qbase) * (size_t)D_;
    float*       attnp = attn + (bq + qbase) * (size_t)L_;

    // ---------------- Phase 0: Q A-fragments (pre-scaled by 1/temper), kept in regs
    bf16x8 aq[2][4];
    #pragma unroll
    for (int h = 0; h < 2; ++h) {
        #pragma unroll
        for (int ds = 0; ds < 4; ++ds) {
            const float* p = qp + (size_t)(h*16 + li) * D_ + ds*32 + lg*8;
            f32x4 x0 = *(const f32x4*)p;
            f32x4 x1 = *(const f32x4*)(p + 4);
            bf16x8 a;
            #pragma unroll
            for (int u = 0; u < 4; ++u) {
                a[u]   = (bf16_t)(x0[u] * SCALE);
                a[4+u] = (bf16_t)(x1[u] * SCALE);
            }
            aq[h][ds] = a;
        }
    }

    // ---------------- Phase 1: S = (Q/temper)·K^T + mask  -> LDS (bf16), per-wave 256 k-columns
    {
        float kraw[32];     // next K tile raw (4 dsteps x 8 floats)
        int   mraw[8];      // next mask (4 regs x 2 halves)

        auto loadK = [&](int t, float* dst) {
            #pragma unroll
            for (int ds = 0; ds < 4; ++ds) {
                const float* p = kp + (size_t)(w*256 + t*16 + li) * D_ + ds*32 + lg*8;
                f32x4 x0 = *(const f32x4*)p;
                f32x4 x1 = *(const f32x4*)(p + 4);
                #pragma unroll
                for (int u = 0; u < 4; ++u) { dst[ds*8+u] = x0[u]; dst[ds*8+4+u] = x1[u]; }
            }
        };
        auto loadM = [&](int t, int* dst) {
            const int col = w*256 + t*16 + li;
            #pragma unroll
            for (int r = 0; r < 4; ++r) {
                dst[r]   = mp[(size_t)(lg*4 + r) * L_ + col];
                dst[4+r] = mp[(size_t)(16 + lg*4 + r) * L_ + col];
            }
        };

        loadK(0, kraw);
        loadM(0, mraw);

        #pragma unroll 1
        for (int t = 0; t < 16; ++t) {
            bf16x8 kf[4];
            #pragma unroll
            for (int ds = 0; ds < 4; ++ds) {
                bf16x8 a;
                #pragma unroll
                for (int u = 0; u < 8; ++u) a[u] = (bf16_t)kraw[ds*8+u];
                kf[ds] = a;
            }
            int mcur[8];
            #pragma unroll
            for (int u = 0; u < 8; ++u) mcur[u] = mraw[u];

            if (t + 1 < 16) { loadK(t+1, kraw); loadM(t+1, mraw); }  // depth-1 prefetch

            f32x4 acc0 = {0.f,0.f,0.f,0.f}, acc1 = {0.f,0.f,0.f,0.f};
            #pragma unroll
            for (int ds = 0; ds < 4; ++ds) {
                acc0 = __builtin_amdgcn_mfma_f32_16x16x32_bf16(aq[0][ds], kf[ds], acc0, 0, 0, 0);
                acc1 = __builtin_amdgcn_mfma_f32_16x16x32_bf16(aq[1][ds], kf[ds], acc1, 0, 0, 0);
            }

            const int col = w*256 + t*16 + li;
            #pragma unroll
            for (int r = 0; r < 4; ++r) {
                float s0 = acc0[r] + (mcur[r]   ? 0.f : NEGINF);
                float s1 = acc1[r] + (mcur[4+r] ? 0.f : NEGINF);
                sc[(lg*4 + r) * PITCH + col]      = (bf16_t)s0;   // C-layout: col=l&15, row=(l>>4)*4+r
                sc[(16 + lg*4 + r) * PITCH + col] = (bf16_t)s1;
            }
        }
    }
    __syncthreads();

    // ---------------- Phase 2: exact row softmax (fp32 math, row resident in LDS)
    {
        const int row = tid >> 4;   // 0..31, 16 threads per row (all in one wave)
        const int c   = tid & 15;
        bf16_t* srow = sc + row * PITCH;

        float m = -3.4e38f;
        #pragma unroll
        for (int j = 0; j < 16; ++j) {
            bf16x8 x = *(const bf16x8*)(srow + (c + j*16) * 8);
            #pragma unroll
            for (int u = 0; u < 8; ++u) m = fmaxf(m, (float)x[u]);
        }
        #pragma unroll
        for (int off = 8; off; off >>= 1) m = fmaxf(m, __shfl_xor(m, off, 16));

        float sum = 0.f;
        #pragma unroll
        for (int j = 0; j < 16; ++j) {
            bf16x8 x = *(bf16x8*)(srow + (c + j*16) * 8);
            bf16x8 e;
            #pragma unroll
            for (int u = 0; u < 8; ++u) {
                float ev = __expf((float)x[u] - m);
                sum += ev;
                e[u] = (bf16_t)ev;
            }
            *(bf16x8*)(srow + (c + j*16) * 8) = e;   // overwrite s with unnormalized p
        }
        #pragma unroll
        for (int off = 8; off; off >>= 1) sum += __shfl_xor(sum, off, 16);
        if (c == 0) inv_l[row] = 1.f / sum;
    }
    __syncthreads();

    // ---------------- Phase 2b: write normalized attn (fp32, coalesced float4)
    {
        #pragma unroll 1
        for (int i = 0; i < 32; ++i) {
            int f  = tid + i * 512;     // float4 index over 32x512
            int rw = f >> 9;
            int c4 = f & 511;
            bf16x4 x = *(const bf16x4*)(sc + rw * PITCH + c4 * 4);
            float il = inv_l[rw];
            f32x4 o;
            o[0] = (float)x[0] * il; o[1] = (float)x[1] * il;
            o[2] = (float)x[2] * il; o[3] = (float)x[3] * il;
            *(f32x4*)(attnp + (size_t)rw * L_ + c4 * 4) = o;
        }
    }

    // ---------------- Phase 3: out = (P·V) * inv_l   (per-wave 16 d-columns)
    {
        const int d0 = w * 16;
        f32x4 acc0 = {0.f,0.f,0.f,0.f}, acc1 = {0.f,0.f,0.f,0.f};
        float bufA[8], bufB[8];

        auto loadV = [&](int ks, float* dst) {
            const float* p = vp + (size_t)(ks*32 + lg*8) * D_ + d0 + li;
            #pragma unroll
            for (int u = 0; u < 8; ++u) dst[u] = p[(size_t)u * D_];
        };

        loadV(0, bufA);
        loadV(1, bufB);

        #pragma unroll 1
        for (int ks = 0; ks < 64; ks += 2) {
            bf16x8 bbA;
            #pragma unroll
            for (int u = 0; u < 8; ++u) bbA[u] = (bf16_t)bufA[u];
            if (ks + 2 < 64) loadV(ks + 2, bufA);     // depth-2 prefetch
            bf16x8 a0 = *(const bf16x8*)(sc + li*PITCH        + ks*32 + lg*8);
            bf16x8 a1 = *(const bf16x8*)(sc + (16+li)*PITCH   + ks*32 + lg*8);
            acc0 = __builtin_amdgcn_mfma_f32_16x16x32_bf16(a0, bbA, acc0, 0, 0, 0);
            acc1 = __builtin_amdgcn_mfma_f32_16x16x32_bf16(a1, bbA, acc1, 0, 0, 0);

            bf16x8 bbB;
            #pragma unroll
            for (int u = 0; u < 8; ++u) bbB[u] = (bf16_t)bufB[u];
            if (ks + 3 < 64) loadV(ks + 3, bufB);
            bf16x8 a0b = *(const bf16x8*)(sc + li*PITCH      + ks*32 + 32 + lg*8);
            bf16x8 a1b = *(const bf16x8*)(sc + (16+li)*PITCH + ks*32 + 32 + lg*8);
            acc0 = __builtin_amdgcn_mfma_f32_16x16x32_bf16(a0b, bbB, acc0, 0, 0, 0);
            acc1 = __builtin_amdgcn_mfma_f32_16x16x32_bf16(a1b, bbB, acc1, 0, 0, 0);
        }

        const int dcol = d0 + li;
        #pragma unroll
        for (int r = 0; r < 4; ++r) {
            int row0 = lg*4 + r;
            int row1 = 16 + lg*4 + r;
            outp[(size_t)row0 * D_ + dcol] = acc0[r] * inv_l[row0];
            outp[(size_t)row1 * D_ + dcol] = acc1[r] * inv_l[row1];
        }
    }
}

extern "C" void kernel_launch(void* const* d_in, const int* in_sizes, int n_in,
                              void* d_out, int out_size, void* d_ws, size_t ws_size,
                              hipStream_t stream) {
    const float* q    = (const float*)d_in[0];
    const float* kk   = (const float*)d_in[1];
    const float* v    = (const float*)d_in[2];
    const int*   mask = (const int*)d_in[3];

    float* out  = (float*)d_out;
    float* attn = out + (size_t)B_ * L_ * D_;   // outputs concatenated: out then attn

    dim3 grid(B_ * (L_ / QT));   // 16 * 64 = 1024 blocks
    dim3 block(512);             // 8 waves
    hipLaunchKernelGGL(sdpa_kernel, grid, block, 0, stream,
                       q, kk, v, mask, out, attn);
}